// Round 3
// baseline (2279.014 us; speedup 1.0000x reference)
//
#include <hip/hip_runtime.h>
#include <hip/hip_bf16.h>

// Problem: B=256, T=512, F=512, H=512. Reference scans over BATCH per timestep
// (flax nn.RNN applied to x[:,t,:]), vmapped over T with fresh zero carry. So
// the final output depends only on t = T-1 = 511:
//   z1 = x[:,511,:] @ Wi1 + b1                        (256 x 2048 GEMM)
//   chain over b: h1[b] = LSTM(z1[b], h1[b-1]; Wh1)
//   chain over b: h2[b] = LSTM(b2 + [h1[b]; h2[b-1]] @ [Wi2; Wh2])  (z2 fused)
//   out = h2 @ Wd + bd                                (256 x 10)
//
// Both chains pipelined in ONE persistent kernel (critical path 257 steps).
// Sync design (round 3): NO flags, NO barriers. Every h element is published
// as an 8-byte atomic pair {f32 value, u32 tag = b+1}; consumers poll the
// pair itself until the tag matches -> ONE memory round trip per step.
// Each reduce group (16 lanes L1 / 32 lanes L2) is wave-local, c_state lives
// in the s==0 lane, so waves free-run with no __syncthreads in the loop.
// Agent-scope atomics reach the coherence point (per-XCD L2s not coherent).

#define HH 512
#define FOURH 2048
#define BB 256
#define NWG1 32   // layer-1 WGs: 16 units each, 512-row dot over 16 lanes
#define NWG2 64   // layer-2 WGs:  8 units each, 1024-row dot over 32 lanes

typedef unsigned long long ull;

__device__ __forceinline__ float sigmoid_acc(float x) {
    return 1.f / (1.f + __expf(-x));
}

// ---------------------------------------------------------------------------
// GEMM: C[M,N] = A[M,K] (row stride lda) @ B[K,N] + bias[N]
// 64x64 tiles, 256 threads, 4x4 microtile, BK=16. M=256, N=2048, K=512.
// ---------------------------------------------------------------------------
__global__ __launch_bounds__(256) void gemm_bias_kernel(
    const float* __restrict__ A, long lda,
    const float* __restrict__ B, const float* __restrict__ bias,
    float* __restrict__ C, int N, int K)
{
    __shared__ float As[16][68];
    __shared__ float Bs[16][68];

    const int tid = threadIdx.x;
    const int m0 = blockIdx.y * 64;
    const int n0 = blockIdx.x * 64;
    const int tx = tid & 15;
    const int ty = tid >> 4;

    const int ar = tid >> 2;
    const int ac = (tid & 3) * 4;
    const int bk = tid >> 4;
    const int bn = (tid & 15) * 4;

    float acc[4][4] = {};

    for (int k0 = 0; k0 < K; k0 += 16) {
        float4 av = *(const float4*)(A + (long)(m0 + ar) * lda + k0 + ac);
        float4 bv = *(const float4*)(B + (long)(k0 + bk) * N + n0 + bn);
        As[ac + 0][ar] = av.x;
        As[ac + 1][ar] = av.y;
        As[ac + 2][ar] = av.z;
        As[ac + 3][ar] = av.w;
        *(float4*)&Bs[bk][bn] = bv;
        __syncthreads();
#pragma unroll
        for (int k = 0; k < 16; ++k) {
            float4 a4 = *(const float4*)&As[k][ty * 4];
            float4 b4 = *(const float4*)&Bs[k][tx * 4];
            acc[0][0] += a4.x * b4.x; acc[0][1] += a4.x * b4.y;
            acc[0][2] += a4.x * b4.z; acc[0][3] += a4.x * b4.w;
            acc[1][0] += a4.y * b4.x; acc[1][1] += a4.y * b4.y;
            acc[1][2] += a4.y * b4.z; acc[1][3] += a4.y * b4.w;
            acc[2][0] += a4.z * b4.x; acc[2][1] += a4.z * b4.y;
            acc[2][2] += a4.z * b4.z; acc[2][3] += a4.z * b4.w;
            acc[3][0] += a4.w * b4.x; acc[3][1] += a4.w * b4.y;
            acc[3][2] += a4.w * b4.z; acc[3][3] += a4.w * b4.w;
        }
        __syncthreads();
    }
#pragma unroll
    for (int i = 0; i < 4; ++i) {
#pragma unroll
        for (int j = 0; j < 4; ++j) {
            int n = n0 + tx * 4 + j;
            C[(long)(m0 + ty * 4 + i) * N + n] = acc[i][j] + bias[n];
        }
    }
}

// ---------------------------------------------------------------------------
// Fused pipelined double-LSTM chain. Grid = 96 WGs x 256 threads.
//   WG w in [0,32):  layer-1, owns h1 units [w*16, w*16+16)
//   WG w in [32,96): layer-2, owns h2 units [(w-32)*8, (w-32)*8+8)
// hp1/hp2: (256 x 512) ull pairs {tag<<32 | f32bits}, tag = row index + 1.
// Memset to 0 before launch; wanted tags are 1..256 so no aliasing.
// ---------------------------------------------------------------------------
__global__ __launch_bounds__(256, 1) void fused_lstm_chain(
    const float* __restrict__ Wh1,   // (512, 2048)
    const float* __restrict__ z1,    // (256, 2048)
    const float* __restrict__ Wi2,   // (512, 2048)
    const float* __restrict__ Wh2,   // (512, 2048)
    const float* __restrict__ b2,    // (2048,)
    ull* hp1,                        // (256, 512) tagged pairs
    ull* hp2)                        // (256, 512) tagged pairs
{
    const int wg = blockIdx.x;
    const int tid = threadIdx.x;

    if (wg < NWG1) {
        // ------------------------- layer 1 -------------------------
        const int u = tid >> 4;        // 0..15 unit within WG
        const int s = tid & 15;        // 0..15 row slice (32 rows each)
        const int col0 = wg * 16 + u;

        float wr0[32], wr1[32], wr2[32], wr3[32];
#pragma unroll
        for (int r = 0; r < 32; ++r) {
            const float* p = Wh1 + (long)(s * 32 + r) * FOURH + col0;
            wr0[r] = p[0];
            wr1[r] = p[512];
            wr2[r] = p[1024];
            wr3[r] = p[1536];
        }

        float c_state = 0.f;

        for (int b = 0; b < BB; ++b) {
            // z prefetch (independent of h; issues before the poll)
            float z0 = 0.f, z1v = 0.f, z2v = 0.f, z3v = 0.f;
            if (s == 0) {
                const float* zp = z1 + (long)b * FOURH + col0;
                z0  = zp[0];
                z1v = zp[512];
                z2v = zp[1024];
                z3v = zp[1536];
            }

            float a0 = 0.f, a1 = 0.f, a2 = 0.f, a3 = 0.f;
            if (b > 0) {
                const ull* hp = hp1 + (long)(b - 1) * HH + s * 32;
                const unsigned want = (unsigned)b;   // tag of row b-1
                ull hv[32];
                for (;;) {
#pragma unroll
                    for (int q = 0; q < 32; ++q)
                        hv[q] = __hip_atomic_load(hp + q, __ATOMIC_RELAXED,
                                                  __HIP_MEMORY_SCOPE_AGENT);
                    unsigned bad = 0;
#pragma unroll
                    for (int q = 0; q < 32; ++q)
                        bad |= ((unsigned)(hv[q] >> 32)) ^ want;
                    if (!bad) break;
                }
#pragma unroll
                for (int q = 0; q < 32; ++q) {
                    float hf = __uint_as_float((unsigned)hv[q]);
                    a0 += wr0[q] * hf;
                    a1 += wr1[q] * hf;
                    a2 += wr2[q] * hf;
                    a3 += wr3[q] * hf;
                }
            }

            // reduce across the 16 row-slices (lanes u*16+s, wave-local)
#pragma unroll
            for (int m = 1; m < 16; m <<= 1) {
                a0 += __shfl_xor(a0, m);
                a1 += __shfl_xor(a1, m);
                a2 += __shfl_xor(a2, m);
                a3 += __shfl_xor(a3, m);
            }

            if (s == 0) {
                float ig = sigmoid_acc(z0 + a0);
                float fg = sigmoid_acc(z1v + a1);
                float gg = tanhf(z2v + a2);
                float og = sigmoid_acc(z3v + a3);
                c_state = fg * c_state + ig * gg;
                float hval = og * tanhf(c_state);
                ull pair = ((ull)(unsigned)(b + 1) << 32) | __float_as_uint(hval);
                __hip_atomic_store(hp1 + (long)b * HH + col0, pair,
                                   __ATOMIC_RELAXED, __HIP_MEMORY_SCOPE_AGENT);
            }
        }
    } else {
        // ------------------------- layer 2 -------------------------
        // Input per step b: y = [h1[b] (rows 0..511); h2[b-1] (rows 512..1023)]
        // against stacked [Wi2; Wh2]. Bias b2 step-invariant, in registers.
        const int v = wg - NWG1;       // 0..63
        const int u = tid >> 5;        // 0..7 unit
        const int s = tid & 31;        // 0..31 row slice (32 rows each)
        const int col0 = v * 8 + u;

        const float* Wsrc = (s < 16)
            ? (Wi2 + (long)(s * 32) * FOURH)
            : (Wh2 + (long)((s - 16) * 32) * FOURH);

        float wr0[32], wr1[32], wr2[32], wr3[32];
#pragma unroll
        for (int r = 0; r < 32; ++r) {
            const float* p = Wsrc + (long)r * FOURH + col0;
            wr0[r] = p[0];
            wr1[r] = p[512];
            wr2[r] = p[1024];
            wr3[r] = p[1536];
        }

        float zb0 = 0.f, zb1 = 0.f, zb2 = 0.f, zb3 = 0.f;
        if (s == 0) {
            zb0 = b2[col0];
            zb1 = b2[col0 + 512];
            zb2 = b2[col0 + 1024];
            zb3 = b2[col0 + 1536];
        }

        float c_state = 0.f;

        for (int b = 0; b < BB; ++b) {
            float a0 = 0.f, a1 = 0.f, a2 = 0.f, a3 = 0.f;
            const bool active = (s < 16) || (b > 0);
            if (active) {
                // s<16: h1[b] (tag b+1, produced 1 pipeline stage ahead)
                // s>=16: h2[b-1] (tag b) — the true serial dependency
                const ull* hp = (s < 16)
                    ? (hp1 + (long)b * HH + s * 32)
                    : (hp2 + (long)(b - 1) * HH + (s - 16) * 32);
                const unsigned want = (unsigned)((s < 16) ? (b + 1) : b);
                ull hv[32];
                for (;;) {
#pragma unroll
                    for (int q = 0; q < 32; ++q)
                        hv[q] = __hip_atomic_load(hp + q, __ATOMIC_RELAXED,
                                                  __HIP_MEMORY_SCOPE_AGENT);
                    unsigned bad = 0;
#pragma unroll
                    for (int q = 0; q < 32; ++q)
                        bad |= ((unsigned)(hv[q] >> 32)) ^ want;
                    if (!bad) break;
                }
#pragma unroll
                for (int q = 0; q < 32; ++q) {
                    float hf = __uint_as_float((unsigned)hv[q]);
                    a0 += wr0[q] * hf;
                    a1 += wr1[q] * hf;
                    a2 += wr2[q] * hf;
                    a3 += wr3[q] * hf;
                }
            }

            // reduce across 32 row-slices (lanes u*32+s, wave-local halves)
#pragma unroll
            for (int m = 1; m < 32; m <<= 1) {
                a0 += __shfl_xor(a0, m);
                a1 += __shfl_xor(a1, m);
                a2 += __shfl_xor(a2, m);
                a3 += __shfl_xor(a3, m);
            }

            if (s == 0) {
                float ig = sigmoid_acc(zb0 + a0);
                float fg = sigmoid_acc(zb1 + a1);
                float gg = tanhf(zb2 + a2);
                float og = sigmoid_acc(zb3 + a3);
                c_state = fg * c_state + ig * gg;
                float hval = og * tanhf(c_state);
                ull pair = ((ull)(unsigned)(b + 1) << 32) | __float_as_uint(hval);
                __hip_atomic_store(hp2 + (long)b * HH + col0, pair,
                                   __ATOMIC_RELAXED, __HIP_MEMORY_SCOPE_AGENT);
            }
        }
    }
}

// ---------------------------------------------------------------------------
// Head: out[b][j] = sum_k h2[b][k] * Wd[k][j] + bd[j].  One wave per row.
// Reads the tagged pairs (low 32 bits = value).
// ---------------------------------------------------------------------------
__global__ __launch_bounds__(64) void head_kernel(
    const ull* __restrict__ hp2, const float* __restrict__ Wd,
    const float* __restrict__ bd, float* __restrict__ out)
{
    const int b = blockIdx.x;
    const int l = threadIdx.x;
    float p[10] = {};
    for (int k = l; k < HH; k += 64) {
        float hv = __uint_as_float((unsigned)hp2[(long)b * HH + k]);
        const float* wrow = Wd + k * 10;
#pragma unroll
        for (int j = 0; j < 10; ++j) p[j] += hv * wrow[j];
    }
#pragma unroll
    for (int m = 1; m < 64; m <<= 1) {
#pragma unroll
        for (int j = 0; j < 10; ++j) p[j] += __shfl_xor(p[j], m);
    }
    if (l == 0) {
#pragma unroll
        for (int j = 0; j < 10; ++j) out[b * 10 + j] = p[j] + bd[j];
    }
}

// ---------------------------------------------------------------------------
extern "C" void kernel_launch(void* const* d_in, const int* in_sizes, int n_in,
                              void* d_out, int out_size, void* d_ws, size_t ws_size,
                              hipStream_t stream)
{
    const float* x   = (const float*)d_in[0];   // (256, 512, 512)
    const float* Wi1 = (const float*)d_in[1];   // (512, 2048)
    const float* Wh1 = (const float*)d_in[2];   // (512, 2048)
    const float* b1  = (const float*)d_in[3];   // (2048,)
    const float* Wi2 = (const float*)d_in[4];
    const float* Wh2 = (const float*)d_in[5];
    const float* b2  = (const float*)d_in[6];
    const float* Wd  = (const float*)d_in[7];   // (512, 10)
    const float* bd  = (const float*)d_in[8];   // (10,)
    float* out = (float*)d_out;

    char* ws = (char*)d_ws;
    float* z1 = (float*)ws;                      // 256*2048*4 = 2 MB
    ull* hp1  = (ull*)(ws + (size_t)2 * 1024 * 1024);        // 1 MB
    ull* hp2  = (ull*)(ws + (size_t)3 * 1024 * 1024);        // 1 MB
    // total ws use: 4 MB

    // Clear tags (ws is re-poisoned 0xAA before every timed launch; memset
    // also guards against stale tags if a prior call left real tags behind).
    hipMemsetAsync(hp1, 0, (size_t)2 * 1024 * 1024, stream);

    // z1 = x[:,511,:] @ Wi1 + b1   (x row stride = T*F = 262144 floats)
    dim3 ggrid(FOURH / 64, BB / 64);   // (32, 4)
    gemm_bias_kernel<<<ggrid, 256, 0, stream>>>(
        x + (long)511 * 512, (long)512 * 512, Wi1, b1, z1, FOURH, HH);

    fused_lstm_chain<<<NWG1 + NWG2, 256, 0, stream>>>(
        Wh1, z1, Wi2, Wh2, b2, hp1, hp2);

    head_kernel<<<BB, 64, 0, stream>>>(hp2, Wd, bd, out);
}

// Round 11
// 1329.502 us; speedup vs baseline: 1.7142x; 1.7142x over previous
//
#include <hip/hip_runtime.h>
#include <hip/hip_bf16.h>

// Problem: B=256, T=512, F=512, H=512. Reference scans over BATCH per timestep
// (flax nn.RNN applied to x[:,t,:]), vmapped over T with fresh zero carry. So
// the final output depends only on t = T-1 = 511:
//   z1 = x[:,511,:] @ Wi1 + b1                        (256 x 2048 GEMM)
//   chain over b: h1[b] = LSTM(z1[b], h1[b-1]; Wh1)
//   chain over b: h2[b] = LSTM(b2 + [h1[b]; h2[b-1]] @ [Wi2; Wh2])  (z2 fused)
//   out = h2 @ Wd + bd                                (256 x 10)
//
// Sync design (round-3 post-mortem: 7.6us/step, pure spin-contention —
// every 8B tagged pair was polled by ~512 threads; uncached agent loads
// serialized at the coherence point). Now:
//   * tagged pairs {f32 value, u32 tag=b+1} remain the publication format
//   * only DESIGNATED POLLER lanes spin (1 lane per producer WG per consumer
//     WG, ~48 pollers per line group instead of ~512)
//   * pollers push values into double-buffered LDS; ONE __syncthreads per
//     step; all threads consume from LDS via float4 (pad-36 layout)
//   * producers store their pairs and continue (no producer barrier)
//   * layer-1 and layer-2-h2 pollers sit in different waves -> poll phases
//     run concurrently

#define HH 512
#define FOURH 2048
#define BB 256
#define NWG1 16   // layer-1 WGs: 512 thr, 32 units each (16-lane dot groups)
#define NWG2 32   // layer-2 WGs: 512 thr, 16 units each (32-lane dot groups)

typedef unsigned long long ull;

__device__ __forceinline__ float sigmoid_acc(float x) {
    return 1.f / (1.f + __expf(-x));
}

// Poll 8 tagged pairs until all tags == want, then write the 8 values to LDS.
__device__ __forceinline__ void poll8(const ull* hp, unsigned want, float* dst) {
    ull hv[8];
    for (;;) {
#pragma unroll
        for (int q = 0; q < 8; ++q)
            hv[q] = __hip_atomic_load(hp + q, __ATOMIC_RELAXED,
                                      __HIP_MEMORY_SCOPE_AGENT);
        unsigned bad = 0;
#pragma unroll
        for (int q = 0; q < 8; ++q)
            bad |= ((unsigned)(hv[q] >> 32)) ^ want;
        if (!bad) break;
    }
    float4 lo = make_float4(__uint_as_float((unsigned)hv[0]),
                            __uint_as_float((unsigned)hv[1]),
                            __uint_as_float((unsigned)hv[2]),
                            __uint_as_float((unsigned)hv[3]));
    float4 hi = make_float4(__uint_as_float((unsigned)hv[4]),
                            __uint_as_float((unsigned)hv[5]),
                            __uint_as_float((unsigned)hv[6]),
                            __uint_as_float((unsigned)hv[7]));
    *(float4*)(dst + 0) = lo;
    *(float4*)(dst + 4) = hi;
}

// ---------------------------------------------------------------------------
// GEMM: C[M,N] = A[M,K] (row stride lda) @ B[K,N] + bias[N]
// 64x64 tiles, 256 threads, 4x4 microtile, BK=16. M=256, N=2048, K=512.
// ---------------------------------------------------------------------------
__global__ __launch_bounds__(256) void gemm_bias_kernel(
    const float* __restrict__ A, long lda,
    const float* __restrict__ B, const float* __restrict__ bias,
    float* __restrict__ C, int N, int K)
{
    __shared__ float As[16][68];
    __shared__ float Bs[16][68];

    const int tid = threadIdx.x;
    const int m0 = blockIdx.y * 64;
    const int n0 = blockIdx.x * 64;
    const int tx = tid & 15;
    const int ty = tid >> 4;

    const int ar = tid >> 2;
    const int ac = (tid & 3) * 4;
    const int bk = tid >> 4;
    const int bn = (tid & 15) * 4;

    float acc[4][4] = {};

    for (int k0 = 0; k0 < K; k0 += 16) {
        float4 av = *(const float4*)(A + (long)(m0 + ar) * lda + k0 + ac);
        float4 bv = *(const float4*)(B + (long)(k0 + bk) * N + n0 + bn);
        As[ac + 0][ar] = av.x;
        As[ac + 1][ar] = av.y;
        As[ac + 2][ar] = av.z;
        As[ac + 3][ar] = av.w;
        *(float4*)&Bs[bk][bn] = bv;
        __syncthreads();
#pragma unroll
        for (int k = 0; k < 16; ++k) {
            float4 a4 = *(const float4*)&As[k][ty * 4];
            float4 b4 = *(const float4*)&Bs[k][tx * 4];
            acc[0][0] += a4.x * b4.x; acc[0][1] += a4.x * b4.y;
            acc[0][2] += a4.x * b4.z; acc[0][3] += a4.x * b4.w;
            acc[1][0] += a4.y * b4.x; acc[1][1] += a4.y * b4.y;
            acc[1][2] += a4.y * b4.z; acc[1][3] += a4.y * b4.w;
            acc[2][0] += a4.z * b4.x; acc[2][1] += a4.z * b4.y;
            acc[2][2] += a4.z * b4.z; acc[2][3] += a4.z * b4.w;
            acc[3][0] += a4.w * b4.x; acc[3][1] += a4.w * b4.y;
            acc[3][2] += a4.w * b4.z; acc[3][3] += a4.w * b4.w;
        }
        __syncthreads();
    }
#pragma unroll
    for (int i = 0; i < 4; ++i) {
#pragma unroll
        for (int j = 0; j < 4; ++j) {
            int n = n0 + tx * 4 + j;
            C[(long)(m0 + ty * 4 + i) * N + n] = acc[i][j] + bias[n];
        }
    }
}

// ---------------------------------------------------------------------------
// Fused pipelined double-LSTM chain. Grid = 48 WGs x 512 threads.
//   WG w in [0,16):  layer-1, units [w*32, w*32+32)
//   WG w in [16,48): layer-2, units [(w-16)*16, (w-16)*16+16)
// hp1/hp2: (256 x 512) ull pairs {tag<<32 | f32bits}, tag = row + 1; memset 0.
// LDS h row buffers: slot(j) = (j>>5)*36 + (j&31)  (pad 36 -> f4-aligned).
// Double-buffer + the single per-step barrier orders step-(b+1) poller
// writes (buf^1) against step-(b-1) readers of the same buffer.
// ---------------------------------------------------------------------------
__global__ __launch_bounds__(512, 1) void fused_lstm_chain(
    const float* __restrict__ Wh1,   // (512, 2048)
    const float* __restrict__ z1g,   // (256, 2048)
    const float* __restrict__ Wi2,   // (512, 2048)
    const float* __restrict__ Wh2,   // (512, 2048)
    const float* __restrict__ b2,    // (2048,)
    ull* hp1,                        // (256, 512) tagged pairs
    ull* hp2)                        // (256, 512) tagged pairs
{
    const int wg = blockIdx.x;
    const int tid = threadIdx.x;

    if (wg < NWG1) {
        // ------------------------- layer 1 -------------------------
        __shared__ float h_sh[2][16 * 36];
        const int u = tid >> 4;        // 0..31 unit
        const int s = tid & 15;        // 0..15 row slice (32 rows each)
        const int col0 = wg * 32 + u;

        float wr0[32], wr1[32], wr2[32], wr3[32];
#pragma unroll
        for (int r = 0; r < 32; ++r) {
            const float* p = Wh1 + (long)(s * 32 + r) * FOURH + col0;
            wr0[r] = p[0];
            wr1[r] = p[512];
            wr2[r] = p[1024];
            wr3[r] = p[1536];
        }

        float c_state = 0.f;

        for (int b = 0; b < BB; ++b) {
            const int buf = b & 1;

            // z prefetch (independent of h; issues before the poll/barrier)
            float z0 = 0.f, z1v = 0.f, z2v = 0.f, z3v = 0.f;
            if (s == 0) {
                const float* zp = z1g + (long)b * FOURH + col0;
                z0  = zp[0];
                z1v = zp[512];
                z2v = zp[1024];
                z3v = zp[1536];
            }

            // designated pollers: lane p polls producer p's 32 pairs of
            // h1 row b-1 (tag b), pushes values to LDS
            if (b > 0 && tid < NWG1) {
                const ull* hp = hp1 + (long)(b - 1) * HH + tid * 32;
                float* dst = &h_sh[buf][tid * 36];
                const unsigned want = (unsigned)b;
#pragma unroll
                for (int c = 0; c < 4; ++c)
                    poll8(hp + c * 8, want, dst + c * 8);
            }
            __syncthreads();

            float a0 = 0.f, a1 = 0.f, a2 = 0.f, a3 = 0.f;
            if (b > 0) {
                const float* hrow = &h_sh[buf][s * 36];
#pragma unroll
                for (int q4 = 0; q4 < 8; ++q4) {
                    float4 hv = *(const float4*)(hrow + q4 * 4);
                    a0 += wr0[4*q4+0]*hv.x + wr0[4*q4+1]*hv.y + wr0[4*q4+2]*hv.z + wr0[4*q4+3]*hv.w;
                    a1 += wr1[4*q4+0]*hv.x + wr1[4*q4+1]*hv.y + wr1[4*q4+2]*hv.z + wr1[4*q4+3]*hv.w;
                    a2 += wr2[4*q4+0]*hv.x + wr2[4*q4+1]*hv.y + wr2[4*q4+2]*hv.z + wr2[4*q4+3]*hv.w;
                    a3 += wr3[4*q4+0]*hv.x + wr3[4*q4+1]*hv.y + wr3[4*q4+2]*hv.z + wr3[4*q4+3]*hv.w;
                }
            }

            // reduce across the 16 row-slices (wave-local 16-lane groups)
#pragma unroll
            for (int m = 1; m < 16; m <<= 1) {
                a0 += __shfl_xor(a0, m);
                a1 += __shfl_xor(a1, m);
                a2 += __shfl_xor(a2, m);
                a3 += __shfl_xor(a3, m);
            }

            if (s == 0) {
                float ig = sigmoid_acc(z0 + a0);
                float fg = sigmoid_acc(z1v + a1);
                float gg = tanhf(z2v + a2);
                float og = sigmoid_acc(z3v + a3);
                c_state = fg * c_state + ig * gg;
                float hval = og * tanhf(c_state);
                ull pair = ((ull)(unsigned)(b + 1) << 32) | __float_as_uint(hval);
                __hip_atomic_store(hp1 + (long)b * HH + col0, pair,
                                   __ATOMIC_RELAXED, __HIP_MEMORY_SCOPE_AGENT);
            }
            // no trailing barrier: double-buffered LDS + next step's barrier
            // order poller writes (buf^1) against this step's readers
        }
    } else {
        // ------------------------- layer 2 -------------------------
        // Input per step b: y = [h1[b] (rows 0..511); h2[b-1] (rows 512..1023)]
        // against stacked [Wi2; Wh2]. Bias b2 step-invariant, in registers.
        __shared__ float y_sh[2][32 * 36];
        const int v = wg - NWG1;       // 0..31
        const int u = tid >> 5;        // 0..15 unit
        const int s = tid & 31;        // 0..31 row slice (32 rows each)
        const int col0 = v * 16 + u;

        const float* Wsrc = (s < 16)
            ? (Wi2 + (long)(s * 32) * FOURH)
            : (Wh2 + (long)((s - 16) * 32) * FOURH);

        float wr0[32], wr1[32], wr2[32], wr3[32];
#pragma unroll
        for (int r = 0; r < 32; ++r) {
            const float* p = Wsrc + (long)r * FOURH + col0;
            wr0[r] = p[0];
            wr1[r] = p[512];
            wr2[r] = p[1024];
            wr3[r] = p[1536];
        }

        float zb0 = 0.f, zb1 = 0.f, zb2 = 0.f, zb3 = 0.f;
        if (s == 0) {
            zb0 = b2[col0];
            zb1 = b2[col0 + 512];
            zb2 = b2[col0 + 1024];
            zb3 = b2[col0 + 1536];
        }

        float c_state = 0.f;

        for (int b = 0; b < BB; ++b) {
            const int buf = b & 1;

            // wave-0 lanes 0..15: poll h1[b] (tag b+1) from L1 producer tid
            // wave-1 lanes 64..95: poll h2[b-1] (tag b) from L2 producer tid-64
            // (separate waves -> the two poll phases overlap)
            if (tid < NWG1) {
                const ull* hp = hp1 + (long)b * HH + tid * 32;
                float* dst = &y_sh[buf][tid * 36];
                const unsigned want = (unsigned)(b + 1);
#pragma unroll
                for (int c = 0; c < 4; ++c)
                    poll8(hp + c * 8, want, dst + c * 8);
            } else if (tid >= 64 && tid < 64 + NWG2 && b > 0) {
                const int m = tid - 64;                    // producer v index
                const ull* hp = hp2 + (long)(b - 1) * HH + m * 16;
                // j = 512 + m*16 + i -> slot (16 + (m>>1))*36 + (m&1)*16 + i
                float* dst = &y_sh[buf][(16 + (m >> 1)) * 36 + (m & 1) * 16];
                const unsigned want = (unsigned)b;
                poll8(hp, want, dst);
                poll8(hp + 8, want, dst + 8);
            }
            __syncthreads();

            float a0 = 0.f, a1 = 0.f, a2 = 0.f, a3 = 0.f;
            if (s < 16 || b > 0) {
                const float* yrow = &y_sh[buf][s * 36];
#pragma unroll
                for (int q4 = 0; q4 < 8; ++q4) {
                    float4 hv = *(const float4*)(yrow + q4 * 4);
                    a0 += wr0[4*q4+0]*hv.x + wr0[4*q4+1]*hv.y + wr0[4*q4+2]*hv.z + wr0[4*q4+3]*hv.w;
                    a1 += wr1[4*q4+0]*hv.x + wr1[4*q4+1]*hv.y + wr1[4*q4+2]*hv.z + wr1[4*q4+3]*hv.w;
                    a2 += wr2[4*q4+0]*hv.x + wr2[4*q4+1]*hv.y + wr2[4*q4+2]*hv.z + wr2[4*q4+3]*hv.w;
                    a3 += wr3[4*q4+0]*hv.x + wr3[4*q4+1]*hv.y + wr3[4*q4+2]*hv.z + wr3[4*q4+3]*hv.w;
                }
            }

            // reduce across 32 row-slices (wave-local 32-lane groups)
#pragma unroll
            for (int m = 1; m < 32; m <<= 1) {
                a0 += __shfl_xor(a0, m);
                a1 += __shfl_xor(a1, m);
                a2 += __shfl_xor(a2, m);
                a3 += __shfl_xor(a3, m);
            }

            if (s == 0) {
                float ig = sigmoid_acc(zb0 + a0);
                float fg = sigmoid_acc(zb1 + a1);
                float gg = tanhf(zb2 + a2);
                float og = sigmoid_acc(zb3 + a3);
                c_state = fg * c_state + ig * gg;
                float hval = og * tanhf(c_state);
                ull pair = ((ull)(unsigned)(b + 1) << 32) | __float_as_uint(hval);
                __hip_atomic_store(hp2 + (long)b * HH + col0, pair,
                                   __ATOMIC_RELAXED, __HIP_MEMORY_SCOPE_AGENT);
            }
        }
    }
}

// ---------------------------------------------------------------------------
// Head: out[b][j] = sum_k h2[b][k] * Wd[k][j] + bd[j].  One wave per row.
// Reads the tagged pairs (low 32 bits = value).
// ---------------------------------------------------------------------------
__global__ __launch_bounds__(64) void head_kernel(
    const ull* __restrict__ hp2, const float* __restrict__ Wd,
    const float* __restrict__ bd, float* __restrict__ out)
{
    const int b = blockIdx.x;
    const int l = threadIdx.x;
    float p[10] = {};
    for (int k = l; k < HH; k += 64) {
        float hv = __uint_as_float((unsigned)hp2[(long)b * HH + k]);
        const float* wrow = Wd + k * 10;
#pragma unroll
        for (int j = 0; j < 10; ++j) p[j] += hv * wrow[j];
    }
#pragma unroll
    for (int m = 1; m < 64; m <<= 1) {
#pragma unroll
        for (int j = 0; j < 10; ++j) p[j] += __shfl_xor(p[j], m);
    }
    if (l == 0) {
#pragma unroll
        for (int j = 0; j < 10; ++j) out[b * 10 + j] = p[j] + bd[j];
    }
}

// ---------------------------------------------------------------------------
extern "C" void kernel_launch(void* const* d_in, const int* in_sizes, int n_in,
                              void* d_out, int out_size, void* d_ws, size_t ws_size,
                              hipStream_t stream)
{
    const float* x   = (const float*)d_in[0];   // (256, 512, 512)
    const float* Wi1 = (const float*)d_in[1];   // (512, 2048)
    const float* Wh1 = (const float*)d_in[2];   // (512, 2048)
    const float* b1  = (const float*)d_in[3];   // (2048,)
    const float* Wi2 = (const float*)d_in[4];
    const float* Wh2 = (const float*)d_in[5];
    const float* b2  = (const float*)d_in[6];
    const float* Wd  = (const float*)d_in[7];   // (512, 10)
    const float* bd  = (const float*)d_in[8];   // (10,)
    float* out = (float*)d_out;

    char* ws = (char*)d_ws;
    ull* hp1  = (ull*)ws;                                    // 1 MB
    ull* hp2  = (ull*)(ws + (size_t)1 * 1024 * 1024);        // 1 MB
    float* z1 = (float*)(ws + (size_t)2 * 1024 * 1024);      // 2 MB
    // total ws use: 4 MB

    // Clear tags (ws poison is 0xAA, which can never equal a wanted tag
    // 1..256, but memset removes any dependence on harness poison behavior).
    hipMemsetAsync(ws, 0, (size_t)2 * 1024 * 1024, stream);

    // z1 = x[:,511,:] @ Wi1 + b1   (x row stride = T*F = 262144 floats)
    dim3 ggrid(FOURH / 64, BB / 64);   // (32, 4)
    gemm_bias_kernel<<<ggrid, 256, 0, stream>>>(
        x + (long)511 * 512, (long)512 * 512, Wi1, b1, z1, FOURH, HH);

    fused_lstm_chain<<<NWG1 + NWG2, 512, 0, stream>>>(
        Wh1, z1, Wi2, Wh2, b2, hp1, hp2);

    head_kernel<<<BB, 64, 0, stream>>>(hp2, Wd, bd, out);
}